// Round 1
// baseline (155.045 us; speedup 1.0000x reference)
//
#include <hip/hip_runtime.h>

// Expansion + checkerboard-preserving dropout.
// out[bc, oh, ow] = keep(oh,ow) ? x[bc, oh/5+oh%5-2, ow/5+ow%5-2] * (1/0.75) : 0
// keep = rand_vals[oh,ow] > 0.25 || (oh%5==2 && ow%5==2); out-of-range x index -> 0.

#define KEEP_SCALE (1.0f / 0.75f)

__global__ __launch_bounds__(256) void expand_cps_dropout_kernel(
    const float* __restrict__ x,          // (1024, 64, 64)
    const float* __restrict__ rand_vals,  // (320, 320)
    float* __restrict__ out,              // (1024, 320, 320)
    int n4)                               // out_size / 4
{
    const int stride = gridDim.x * blockDim.x;
    for (int i = blockIdx.x * blockDim.x + threadIdx.x; i < n4; i += stride) {
        // i = (bc*320 + oh)*80 + ow4   (80 float4 per 320-wide row)
        int ow4  = i % 80;
        int rest = i / 80;
        int oh   = rest % 320;
        int bc   = rest / 320;

        // vertical source row (same for all 4 elements)
        int ohq = oh / 5;
        int ohr = oh - ohq * 5;
        int ih  = ohq + ohr - 2;
        bool ih_ok = ((unsigned)ih < 64u);
        bool oh_center = (ohr == 2);

        const float4 rv =
            *reinterpret_cast<const float4*>(rand_vals + oh * 320 + ow4 * 4);
        const float* xrow = x + ((size_t)bc * 64 + (ih_ok ? ih : 0)) * 64;

        float4 o;
        float*       op = &o.x;
        const float* rp = &rv.x;
        int ow = ow4 * 4;
        #pragma unroll
        for (int k = 0; k < 4; ++k) {
            int owk = ow + k;
            int owq = owk / 5;
            int owr = owk - owq * 5;
            int iw  = owq + owr - 2;
            bool in_bounds = ih_ok && ((unsigned)iw < 64u);
            float xv = in_bounds ? xrow[iw] : 0.0f;
            bool keep = (rp[k] > 0.25f) || (oh_center && (owr == 2));
            op[k] = keep ? xv * KEEP_SCALE : 0.0f;
        }
        *reinterpret_cast<float4*>(out + (size_t)i * 4) = o;
    }
}

extern "C" void kernel_launch(void* const* d_in, const int* in_sizes, int n_in,
                              void* d_out, int out_size, void* d_ws, size_t ws_size,
                              hipStream_t stream) {
    const float* x  = (const float*)d_in[0];
    const float* rv = (const float*)d_in[1];
    float* out      = (float*)d_out;

    int n4 = out_size / 4;  // 26,214,400 float4s
    dim3 block(256);
    dim3 grid(2048);        // 2048*256 = 524,288 threads -> 50 iters each
    hipLaunchKernelGGL(expand_cps_dropout_kernel, grid, block, 0, stream,
                       x, rv, out, n4);
}

// Round 2
// 136.844 us; speedup vs baseline: 1.1330x; 1.1330x over previous
//
#include <hip/hip_runtime.h>

// Expansion + checkerboard-preserving dropout.
// out[bc, oh, ow] = keep(oh,ow) ? x[bc, oh/5+oh%5-2, ow/5+ow%5-2] * (1/0.75) : 0
// keep = rand_vals[oh,ow] > 0.25 || (oh%5==2 && ow%5==2); out-of-range x index -> 0.
//
// Layout: block = 320 threads (5 waves) covers 16 contiguous output rows of one
// (b,c) image (= 1280 float4). Thread t owns ow4 = t%80, rows rg*16 + t/80 + 4j
// (j=0..3). Stores & rand loads are contiguous 5 KB per unrolled j. The
// ow-pattern (iw, center-col, w-bounds) is computed once per thread and reused
// across the 4 rows.

#define KEEP_SCALE (1.0f / 0.75f)

__global__ __launch_bounds__(320) void expand_cps_dropout_kernel(
    const float* __restrict__ x,          // (1024, 64, 64)
    const float* __restrict__ rand_vals,  // (320, 320)
    float* __restrict__ out)              // (1024, 320, 320)
{
    const int t  = threadIdx.x;   // 0..319
    const int rg = blockIdx.x;    // 0..19  (group of 16 rows)
    const int bc = blockIdx.y;    // 0..1023

    const int ow4  = t % 80;
    const int ohL0 = t / 80;      // 0..3
    const int ow   = ow4 * 4;

    // Per-thread ow-pattern, computed once, reused for all 4 rows.
    int  iw[4];
    bool wok[4];
    bool wc[4];
    #pragma unroll
    for (int k = 0; k < 4; ++k) {
        int owk = ow + k;
        int q   = owk / 5;
        int r   = owk - q * 5;
        iw[k]  = q + r - 2;
        wok[k] = ((unsigned)iw[k] < 64u);
        wc[k]  = (r == 2);
    }

    const int oh0 = rg * 16 + ohL0;                     // row for j=0
    const float* xbase = x + (size_t)bc * 4096;         // 64*64 image
    const float* rvp   = rand_vals + (size_t)oh0 * 320 + ow;
    float*       outp  = out + (size_t)bc * 102400 + (size_t)oh0 * 320 + ow;

    #pragma unroll
    for (int j = 0; j < 4; ++j) {
        const int oh = oh0 + 4 * j;
        const int q  = oh / 5;
        const int r  = oh - q * 5;
        const int ih = q + r - 2;
        const bool hok = ((unsigned)ih < 64u);
        const bool hc  = (r == 2);

        const float* xrow = xbase + (hok ? ih : 0) * 64;
        const float4 rvv = *reinterpret_cast<const float4*>(rvp + (size_t)j * 4 * 320);
        const float* rp = &rvv.x;

        float4 o;
        float* op = &o.x;
        #pragma unroll
        for (int k = 0; k < 4; ++k) {
            float xv  = (hok && wok[k]) ? xrow[iw[k]] : 0.0f;
            bool keep = (rp[k] > 0.25f) || (hc && wc[k]);
            op[k] = keep ? xv * KEEP_SCALE : 0.0f;
        }
        *reinterpret_cast<float4*>(outp + (size_t)j * 4 * 320) = o;
    }
}

extern "C" void kernel_launch(void* const* d_in, const int* in_sizes, int n_in,
                              void* d_out, int out_size, void* d_ws, size_t ws_size,
                              hipStream_t stream) {
    const float* x  = (const float*)d_in[0];
    const float* rv = (const float*)d_in[1];
    float* out      = (float*)d_out;

    dim3 block(320);
    dim3 grid(20, 1024);   // 20 row-groups x 1024 (b*c) images
    hipLaunchKernelGGL(expand_cps_dropout_kernel, grid, block, 0, stream,
                       x, rv, out);
}

// Round 3
// 97.332 us; speedup vs baseline: 1.5929x; 1.4059x over previous
//
#include <hip/hip_runtime.h>
#include <stdint.h>

// Expansion + checkerboard-preserving dropout, two-phase.
// Phase 1: pack mask bits (rand>0.25 | center) into 3200 u32 words in d_ws.
// Phase 2: per block, stage zero-padded x rows + mask words in LDS; inner loop
//          is 4 LDS reads + 1 mask word + 1 float4 store per 16B of output.

#define KEEP_SCALE (1.0f / 0.75f)

__global__ __launch_bounds__(256) void build_mask_kernel(
    const float* __restrict__ rv,       // (320,320)
    uint32_t* __restrict__ mask)        // 3200 words, 10 per row
{
    int w = blockIdx.x * 256 + threadIdx.x;
    if (w >= 3200) return;
    int oh  = w / 10;
    int ow0 = (w - oh * 10) * 32;
    bool hc = (oh % 5) == 2;
    const float* rp = rv + oh * 320 + ow0;
    uint32_t m = 0;
    #pragma unroll
    for (int b = 0; b < 32; ++b) {
        int r = (ow0 + b) % 5;          // compile-time pattern per b after const-fold of ow0%5? keep general
        bool keep = (rp[b] > 0.25f) || (hc && r == 2);
        m |= (uint32_t)keep << b;
    }
    mask[w] = m;
}

__global__ __launch_bounds__(320) void expand_cps_dropout_kernel(
    const float* __restrict__ x,        // (1024, 64, 64)
    const uint32_t* __restrict__ mask,  // 3200 words
    float* __restrict__ out)            // (1024, 320, 320)
{
    __shared__ float    xs[20 * 68];    // 20 padded source rows, 68 cols (2 zero each side)
    __shared__ uint32_t ms[640];        // 64 rows x 10 mask words

    const int t  = threadIdx.x;         // 0..319
    const int rg = blockIdx.x;          // 0..4   (64-row group)
    const int bc = blockIdx.y;          // 0..1023

    const int oh_blk  = rg * 64;
    const int ih_base = oh_blk / 5 - 2;           // first staged source row (may be -2)
    const float* xi = x + (size_t)bc * 4096;

    // Stage zero-padded x rows: xs[sr][c] = x[ih_base+sr][c-2] or 0.
    for (int idx = t; idx < 20 * 68; idx += 320) {
        int sr = idx / 68;
        int c  = idx - sr * 68;
        int gih = ih_base + sr;
        int giw = c - 2;
        float v = 0.0f;
        if ((unsigned)gih < 64u && (unsigned)giw < 64u)
            v = xi[gih * 64 + giw];
        xs[idx] = v;
    }
    // Stage mask words for this row group (contiguous).
    for (int idx = t; idx < 640; idx += 320)
        ms[idx] = mask[rg * 640 + idx];
    __syncthreads();

    const int ow4 = t % 80;
    const int ohL = t / 80;             // 0..3
    const int ow  = ow4 * 4;

    // Padded source-column indices (iw + 2), fixed per thread.
    int iwp[4];
    #pragma unroll
    for (int k = 0; k < 4; ++k) {
        int o5 = ow + k;
        int q  = o5 / 5;
        int r  = o5 - q * 5;
        iwp[k] = q + r;                 // (q + r - 2) + 2
    }
    const int mw  = ow4 >> 3;           // mask word within row
    const int msh = (ow4 & 7) * 4;      // bit shift within word

    float* op = out + (size_t)bc * 102400 + (size_t)(oh_blk + ohL) * 320 + ow;

    #pragma unroll
    for (int j = 0; j < 16; ++j) {
        int row = ohL + 4 * j;          // local output row 0..63
        int ohg = oh_blk + row;
        int q   = ohg / 5;
        int r   = ohg - q * 5;
        int sr  = q + r - 2 - ih_base;  // staged row index, 0..17
        const float* xr = xs + sr * 68;
        uint32_t mb = ms[row * 10 + mw] >> msh;

        float4 o;
        o.x = (mb & 1u) ? xr[iwp[0]] * KEEP_SCALE : 0.0f;
        o.y = (mb & 2u) ? xr[iwp[1]] * KEEP_SCALE : 0.0f;
        o.z = (mb & 4u) ? xr[iwp[2]] * KEEP_SCALE : 0.0f;
        o.w = (mb & 8u) ? xr[iwp[3]] * KEEP_SCALE : 0.0f;
        *reinterpret_cast<float4*>(op + (size_t)(4 * j) * 320) = o;
    }
}

extern "C" void kernel_launch(void* const* d_in, const int* in_sizes, int n_in,
                              void* d_out, int out_size, void* d_ws, size_t ws_size,
                              hipStream_t stream) {
    const float* x  = (const float*)d_in[0];
    const float* rv = (const float*)d_in[1];
    float* out      = (float*)d_out;
    uint32_t* mask  = (uint32_t*)d_ws;      // 12.8 KB

    hipLaunchKernelGGL(build_mask_kernel, dim3(13), dim3(256), 0, stream, rv, mask);

    dim3 block(320);
    dim3 grid(5, 1024);                     // 5 row-groups x 1024 images
    hipLaunchKernelGGL(expand_cps_dropout_kernel, grid, block, 0, stream,
                       x, mask, out);
}